// Round 16
// baseline (263.808 us; speedup 1.0000x reference)
//
#include <hip/hip_runtime.h>
#include <hip/hip_bf16.h>

#define NN 50000
#define NE 600000

typedef __attribute__((ext_vector_type(8))) short short8v;   // 8 bf16 = 4 VGPRs
typedef __attribute__((ext_vector_type(4))) float float4v;   // MFMA C/D

// Dataset facts (pinned on HW over R3-R8): floats fp32, edges int32, out fp32.
__device__ __forceinline__ float bf2f_u(unsigned short u) {
    union { unsigned int i; float f; } v; v.i = ((unsigned int)u) << 16; return v.f;
}
__device__ __forceinline__ unsigned short f2bf_u(float f) {
    __hip_bfloat16 b = __float2bfloat16(f);
    return *reinterpret_cast<unsigned short*>(&b);
}

// ---------------------------------------------------------------------------
// W prep: fp32 W[k][n] -> bf16 Wt[n][k], both weights.
// (R14: in-GEMM transpose = 16-way LDS conflicts. Keep pre-transposed.)
// ---------------------------------------------------------------------------
__global__ __launch_bounds__(256) void prep_wt(const float* __restrict__ W1,
                                               const float* __restrict__ W2,
                                               unsigned short* __restrict__ wt1,
                                               unsigned short* __restrict__ wt2) {
    int t = blockIdx.x * 256 + threadIdx.x;        // 0..32767
    const float* src = (t < 16384) ? W1 : W2;
    unsigned short* dst = (t < 16384) ? wt1 : wt2;
    int idx = t & 16383;
    int n = idx >> 7, k = idx & 127;
    dst[idx] = f2bf_u(src[k * 128 + n]);
}

// ---------------------------------------------------------------------------
// CSR count: separate kernel, 0 LDS (R15 lesson: fused into the GEMM kernel
// it inherited 53KB static LDS -> 3 blocks/CU -> atomics latency-starved,
// mega1=45us. Separate runs at full occupancy.)
// ---------------------------------------------------------------------------
__global__ __launch_bounds__(256) void csr_count(const int* __restrict__ ei,
                                                 int* __restrict__ cnt) {
    int e = blockIdx.x * 256 + threadIdx.x;
    if (e >= NE) return;
    int d = ei[NE + e];
    d = min(max(d, 0), NN - 1);
    atomicAdd(&cnt[d], 1);
}

// ---------------------------------------------------------------------------
// MFMA bf16 GEMM + fused attention-logit epilogue (R11 core).
// Wt pre-transposed bf16 [n][k]; XF32=1: X fp32 (convert on stage).
// C/D layout (m97): col=ct*16+m, row=wrow+q*4+r; head=ct>>1 for H=4.
// ---------------------------------------------------------------------------
template<int H, int XF32>
__global__ __launch_bounds__(256) void gemm_fused(const void* __restrict__ X,
                                                  const unsigned short* __restrict__ Wt,
                                                  const float* __restrict__ a_src,
                                                  const float* __restrict__ a_dst,
                                                  unsigned short* __restrict__ Hout,
                                                  float* __restrict__ als,
                                                  float* __restrict__ ald, int n) {
    __shared__ unsigned short Xs[64][136];
    __shared__ unsigned short WtS[128][136];
    __shared__ float as_s[128], ad_s[128];
    const int tid = threadIdx.x;
    const int row0 = blockIdx.x * 64;

    if (tid < 128) { as_s[tid] = a_src[tid]; ad_s[tid] = a_dst[tid]; }
    {   // stage pre-transposed Wt: pure uint4 copies (conflict-free)
        const uint4* Wv = (const uint4*)Wt;
#pragma unroll
        for (int i = 0; i < 8; ++i) {
            int lin = tid + 256 * i;              // 0..2047
            int r = lin >> 4, c8 = lin & 15;
            *(uint4*)&WtS[r][c8 * 8] = Wv[lin];
        }
    }
    if (XF32) {
        const float4* Xv = (const float4*)X;
#pragma unroll
        for (int i = 0; i < 8; ++i) {
            int lin = tid + 256 * i;
            int r = lin >> 5, c4 = lin & 31;
            float4 v = make_float4(0.f, 0.f, 0.f, 0.f);
            if (row0 + r < n) v = Xv[(size_t)(row0 + r) * 32 + c4];
            ushort4 o;
            o.x = f2bf_u(v.x); o.y = f2bf_u(v.y); o.z = f2bf_u(v.z); o.w = f2bf_u(v.w);
            *(ushort4*)&Xs[r][c4 * 4] = o;
        }
    } else {
        const uint4* Xv = (const uint4*)X;
#pragma unroll
        for (int i = 0; i < 4; ++i) {
            int lin = tid + 256 * i;
            int r = lin >> 4, c8 = lin & 15;
            uint4 v = make_uint4(0u, 0u, 0u, 0u);
            if (row0 + r < n) v = Xv[(size_t)(row0 + r) * 16 + c8];
            *(uint4*)&Xs[r][c8 * 8] = v;
        }
    }
    __syncthreads();

    const int lane = tid & 63;
    const int wrow = (tid >> 6) * 16;
    const int m = lane & 15, q = lane >> 4;

    float4v acc[8];
#pragma unroll
    for (int ct = 0; ct < 8; ++ct) acc[ct] = (float4v){0.f, 0.f, 0.f, 0.f};

#pragma unroll
    for (int kt = 0; kt < 4; ++kt) {
        short8v af = *(const short8v*)&Xs[wrow + m][kt * 32 + q * 8];
#pragma unroll
        for (int ct = 0; ct < 8; ++ct) {
            short8v bf = *(const short8v*)&WtS[ct * 16 + m][kt * 32 + q * 8];
            acc[ct] = __builtin_amdgcn_mfma_f32_16x16x32_bf16(af, bf, acc[ct], 0, 0, 0);
        }
    }

    // store H (bf16)
#pragma unroll
    for (int ct = 0; ct < 8; ++ct)
#pragma unroll
        for (int r = 0; r < 4; ++r) {
            int grow = row0 + wrow + q * 4 + r;
            if (grow < n) Hout[(size_t)grow * 128 + ct * 16 + m] = f2bf_u(acc[ct][r]);
        }

    // fused als/ald epilogue (fp32 accumulators)
#pragma unroll
    for (int r = 0; r < 4; ++r) {
        int grow = row0 + wrow + q * 4 + r;
        if (H == 4) {
            float ps[4], pd[4];
#pragma unroll
            for (int hd = 0; hd < 4; ++hd) {
                float x0 = acc[2 * hd][r], x1 = acc[2 * hd + 1][r];
                ps[hd] = x0 * as_s[hd * 32 + m] + x1 * as_s[hd * 32 + 16 + m];
                pd[hd] = x0 * ad_s[hd * 32 + m] + x1 * ad_s[hd * 32 + 16 + m];
#pragma unroll
                for (int o = 1; o < 16; o <<= 1) {
                    ps[hd] += __shfl_xor(ps[hd], o);
                    pd[hd] += __shfl_xor(pd[hd], o);
                }
            }
            if (m == 0 && grow < n) {
#pragma unroll
                for (int hd = 0; hd < 4; ++hd) {
                    als[(size_t)grow * 4 + hd] = ps[hd];
                    ald[(size_t)grow * 4 + hd] = pd[hd];
                }
            }
        } else {
            float ps = 0.f, pd = 0.f;
#pragma unroll
            for (int ct = 0; ct < 8; ++ct) {
                float xv = acc[ct][r];
                ps += xv * as_s[ct * 16 + m];
                pd += xv * ad_s[ct * 16 + m];
            }
#pragma unroll
            for (int o = 1; o < 16; o <<= 1) {
                ps += __shfl_xor(ps, o);
                pd += __shfl_xor(pd, o);
            }
            if (m == 0 && grow < n) { als[grow] = ps; ald[grow] = pd; }
        }
    }
}

// ---------------------------------------------------------------------------
// CSR alloc: block-local scan + one atomicAdd for block base (R14).
// ---------------------------------------------------------------------------
__global__ __launch_bounds__(256) void csr_alloc(const int* __restrict__ cnt,
                                                 int* __restrict__ off,
                                                 int* __restrict__ cursor,
                                                 int* __restrict__ gbase) {
    __shared__ int tmp[256];
    __shared__ int blockBase;
    const int t = threadIdx.x;
    int g = blockIdx.x * 256 + t;
    int v = (g < NN) ? cnt[g] : 0;
    tmp[t] = v;
    __syncthreads();
    for (int ofs = 1; ofs < 256; ofs <<= 1) {
        int add = (t >= ofs) ? tmp[t - ofs] : 0;
        __syncthreads();
        tmp[t] += add;
        __syncthreads();
    }
    if (t == 255) blockBase = atomicAdd(gbase, tmp[255]);
    __syncthreads();
    if (g < NN) {
        int o = blockBase + tmp[t] - v;
        off[g] = o;
        cursor[g] = o;
    }
}

__global__ __launch_bounds__(256) void csr_fill(const int* __restrict__ ei,
                                                int* __restrict__ cursor,
                                                int* __restrict__ csrc) {
    int e = blockIdx.x * 256 + threadIdx.x;
    if (e >= NE) return;
    int s = ei[e], d = ei[NE + e];
    s = min(max(s, 0), NN - 1);
    d = min(max(d, 0), NN - 1);
    int pos = atomicAdd(&cursor[d], 1);
    csrc[pos] = s;
}

// ---------------------------------------------------------------------------
// Aggregate v2 (R16): one wave per node, FOUR 16-lane edge-groups.
// R15 profile: VALUBusy 80% -> VALU-bound; 16 lanes/head computed identical
// exp chains (16x redundant) + narrow 4B gathers. Now: lane covers 8
// channels (one uint4 = 16B gather), group g handles edges j≡g (mod 4),
// 2-deep batching; exp redundancy 16x->4x, ~2x less VALU/edge. Groups
// combine via shfl_xor(16,32) -- no LDS, no syncthreads (R12 lesson).
// FINAL=0: +bias, ELU, bf16 out. FINAL=1: +bias, fp32 out. No atomics.
// ---------------------------------------------------------------------------
template<int H, int FINAL>
__global__ __launch_bounds__(256) void aggregate(const int* __restrict__ off,
                                                 const int* __restrict__ cnt,
                                                 const int* __restrict__ csrc,
                                                 const unsigned short* __restrict__ h,
                                                 const float* __restrict__ als,
                                                 const float* __restrict__ ald,
                                                 const float* __restrict__ bias,
                                                 void* __restrict__ out) {
    int wid = (int)((blockIdx.x * 256 + threadIdx.x) >> 6);
    int lane = threadIdx.x & 63;
    if (wid >= NN) return;
    const int d = wid;
    const int g = lane >> 4;           // edge group 0..3
    const int c0 = (lane & 15) * 8;    // this lane's 8 channels
    const int hd = (H == 4) ? (c0 >> 5) : 0;
    const float aldd = (H == 4) ? ald[(size_t)d * 4 + hd] : ald[d];

    float acc[8] = {0.f, 0.f, 0.f, 0.f, 0.f, 0.f, 0.f, 0.f};
    float den = 0.f;

    auto expw = [&](float av) {
        float v = av + aldd;
        v = v > 0.f ? v : 0.2f * v;
        return __expf(fminf(v, 60.f));
    };
    auto accum = [&](uint4 hv, float ex) {
        const unsigned short* u = (const unsigned short*)&hv;
#pragma unroll
        for (int i = 0; i < 8; ++i) acc[i] += ex * bf2f_u(u[i]);
        den += ex;
    };

    if (g == 0) {   // self-loop handled by group 0 only
        float av = (H == 4) ? als[(size_t)d * 4 + hd] : als[d];
        uint4 hv = *(const uint4*)&h[(size_t)d * 128 + c0];
        accum(hv, expw(av));
    }

    const int beg = off[d];
    const int end = beg + cnt[d];
    for (int j0 = beg; j0 < end; j0 += 8) {
        int ja = j0 + g, jb = j0 + 4 + g;
        int ia = csrc[min(ja, end - 1)];
        int ib = csrc[min(jb, end - 1)];
        uint4 ha = *(const uint4*)&h[(size_t)ia * 128 + c0];
        uint4 hb = *(const uint4*)&h[(size_t)ib * 128 + c0];
        float aa = (H == 4) ? als[(size_t)ia * 4 + hd] : als[ia];
        float ab = (H == 4) ? als[(size_t)ib * 4 + hd] : als[ib];
        float exa = expw(aa); exa = (ja < end) ? exa : 0.f;
        float exb = expw(ab); exb = (jb < end) ? exb : 0.f;
        accum(ha, exa);
        accum(hb, exb);
    }

    // combine the 4 groups: butterfly over lanes 16, 32 apart
#pragma unroll
    for (int o = 16; o < 64; o <<= 1) {
#pragma unroll
        for (int i = 0; i < 8; ++i) acc[i] += __shfl_xor(acc[i], o);
        den += __shfl_xor(den, o);
    }
    if (g != 0) return;

    const float inv = 1.f / den;
    float4 b0 = *(const float4*)&bias[c0];
    float4 b1 = *(const float4*)&bias[c0 + 4];
    float v[8];
    v[0] = acc[0] * inv + b0.x; v[1] = acc[1] * inv + b0.y;
    v[2] = acc[2] * inv + b0.z; v[3] = acc[3] * inv + b0.w;
    v[4] = acc[4] * inv + b1.x; v[5] = acc[5] * inv + b1.y;
    v[6] = acc[6] * inv + b1.z; v[7] = acc[7] * inv + b1.w;
    if (FINAL) {
        float* op = (float*)out + (size_t)d * 128 + c0;
        *(float4*)op       = make_float4(v[0], v[1], v[2], v[3]);
        *(float4*)(op + 4) = make_float4(v[4], v[5], v[6], v[7]);
    } else {
#pragma unroll
        for (int i = 0; i < 8; ++i) v[i] = v[i] > 0.f ? v[i] : expm1f(v[i]);
        unsigned int p[4];
#pragma unroll
        for (int i = 0; i < 4; ++i)
            p[i] = (unsigned int)f2bf_u(v[2 * i]) | ((unsigned int)f2bf_u(v[2 * i + 1]) << 16);
        *(uint4*)((unsigned short*)out + (size_t)d * 128 + c0) =
            make_uint4(p[0], p[1], p[2], p[3]);
    }
}

// ---------------------------------------------------------------------------
extern "C" void kernel_launch(void* const* d_in, const int* in_sizes, int n_in,
                              void* d_out, int out_size, void* d_ws, size_t ws_size,
                              hipStream_t stream) {
    const float* x      = (const float*)d_in[0];
    const int*   ei     = (const int*)d_in[1];
    const float* W1     = (const float*)d_in[2];
    const float* a_src1 = (const float*)d_in[3];
    const float* a_dst1 = (const float*)d_in[4];
    const float* b1     = (const float*)d_in[5];
    const float* W2     = (const float*)d_in[6];
    const float* a_src2 = (const float*)d_in[7];
    const float* a_dst2 = (const float*)d_in[8];
    const float* b2     = (const float*)d_in[9];

    const int N = NN;

    // Workspace: explicit BYTE offsets, every buffer 16B-aligned.
    char* base = (char*)d_ws;
    int*   cnt    = (int*)(base + 0);          //  50000 i [0, 200000)
    int*   gbase  = (int*)(base + 200000);     //      1 i (memset with cnt)
    int*   off    = (int*)(base + 200016);     //  50000 i
    int*   cursor = (int*)(base + 400016);     //  50000 i
    int*   csrc   = (int*)(base + 602064);     // 600000 i
    float* als    = (float*)(base + 3002064);  // 200000 f
    float* ald    = (float*)(base + 3802064);  // 200000 f
    unsigned short* h   = (unsigned short*)(base + 4602064);   // N*128 bf16
    unsigned short* x2  = (unsigned short*)(base + 17402064);  // N*128 bf16
    unsigned short* wt1 = (unsigned short*)(base + 30202064);  // 16384 bf16
    unsigned short* wt2 = (unsigned short*)(base + 30234832);  // 16384 bf16
    // total ~30.27 MB

    const int gemmGrid  = (N + 63) / 64;          // 782
    const int edgeGrid  = (NE + 255) / 256;       // 2344
    const int allocGrid = (N + 255) / 256;        // 196
    const int aggGrid   = (N * 64 + 255) / 256;   // 12500

    (void)hipMemsetAsync(cnt, 0, 200016, stream);            // cnt + gbase
    prep_wt<<<128, 256, 0, stream>>>(W1, W2, wt1, wt2);
    csr_count<<<edgeGrid, 256, 0, stream>>>(ei, cnt);
    gemm_fused<4, 1><<<gemmGrid, 256, 0, stream>>>(x, wt1, a_src1, a_dst1, h, als, ald, N);
    csr_alloc<<<allocGrid, 256, 0, stream>>>(cnt, off, cursor, gbase);
    csr_fill<<<edgeGrid, 256, 0, stream>>>(ei, cursor, csrc);

    aggregate<4, 0><<<aggGrid, 256, 0, stream>>>(off, cnt, csrc, h, als, ald, b1, x2);
    gemm_fused<1, 0><<<gemmGrid, 256, 0, stream>>>(x2, wt2, a_src2, a_dst2, h, als, ald, N);
    aggregate<1, 1><<<aggGrid, 256, 0, stream>>>(off, cnt, csrc, h, als, ald, b2, d_out);
}

// Round 17
// 256.319 us; speedup vs baseline: 1.0292x; 1.0292x over previous
//
#include <hip/hip_runtime.h>
#include <hip/hip_bf16.h>

#define NN 50000
#define NE 600000

typedef __attribute__((ext_vector_type(8))) short short8v;   // 8 bf16 = 4 VGPRs
typedef __attribute__((ext_vector_type(4))) float float4v;   // MFMA C/D

// Dataset facts (pinned on HW over R3-R8): floats fp32, edges int32, out fp32.
__device__ __forceinline__ float bf2f_u(unsigned short u) {
    union { unsigned int i; float f; } v; v.i = ((unsigned int)u) << 16; return v.f;
}
__device__ __forceinline__ unsigned short f2bf_u(float f) {
    __hip_bfloat16 b = __float2bfloat16(f);
    return *reinterpret_cast<unsigned short*>(&b);
}

// ---------------------------------------------------------------------------
// prep+zero: blocks [0,128) convert fp32 W[k][n] -> bf16 Wt[n][k] (both Ws);
// blocks [128,324) zero cnt + gbase. Replaces the separate memset dispatch.
// ---------------------------------------------------------------------------
__global__ __launch_bounds__(256) void prep_zero(const float* __restrict__ W1,
                                                 const float* __restrict__ W2,
                                                 unsigned short* __restrict__ wt1,
                                                 unsigned short* __restrict__ wt2,
                                                 int* __restrict__ cnt,
                                                 int* __restrict__ gbase) {
    int b = blockIdx.x;
    if (b < 128) {
        int t = b * 256 + threadIdx.x;             // 0..32767
        const float* src = (t < 16384) ? W1 : W2;
        unsigned short* dst = (t < 16384) ? wt1 : wt2;
        int idx = t & 16383;
        int n = idx >> 7, k = idx & 127;
        dst[idx] = f2bf_u(src[k * 128 + n]);
        return;
    }
    int g = (b - 128) * 256 + threadIdx.x;
    if (g < NN) cnt[g] = 0;
    if (b == 128 && threadIdx.x == 0) *gbase = 0;
}

// ---------------------------------------------------------------------------
// CSR count: separate, 0 LDS (R15: fusing into GEMM cost occupancy).
// ---------------------------------------------------------------------------
__global__ __launch_bounds__(256) void csr_count(const int* __restrict__ ei,
                                                 int* __restrict__ cnt) {
    int e = blockIdx.x * 256 + threadIdx.x;
    if (e >= NE) return;
    int d = ei[NE + e];
    d = min(max(d, 0), NN - 1);
    atomicAdd(&cnt[d], 1);
}

// ---------------------------------------------------------------------------
// MFMA bf16 GEMM + fused attention-logit epilogue (R11 core).
// Wt pre-transposed bf16 [n][k]; XF32=1: X fp32 (convert on stage).
// C/D layout (m97): col=ct*16+m, row=wrow+q*4+r; head=ct>>1 for H=4.
// ---------------------------------------------------------------------------
template<int H, int XF32>
__global__ __launch_bounds__(256) void gemm_fused(const void* __restrict__ X,
                                                  const unsigned short* __restrict__ Wt,
                                                  const float* __restrict__ a_src,
                                                  const float* __restrict__ a_dst,
                                                  unsigned short* __restrict__ Hout,
                                                  float* __restrict__ als,
                                                  float* __restrict__ ald, int n) {
    __shared__ unsigned short Xs[64][136];
    __shared__ unsigned short WtS[128][136];
    __shared__ float as_s[128], ad_s[128];
    const int tid = threadIdx.x;
    const int row0 = blockIdx.x * 64;

    if (tid < 128) { as_s[tid] = a_src[tid]; ad_s[tid] = a_dst[tid]; }
    {   // stage pre-transposed Wt: pure uint4 copies (conflict-free)
        const uint4* Wv = (const uint4*)Wt;
#pragma unroll
        for (int i = 0; i < 8; ++i) {
            int lin = tid + 256 * i;              // 0..2047
            int r = lin >> 4, c8 = lin & 15;
            *(uint4*)&WtS[r][c8 * 8] = Wv[lin];
        }
    }
    if (XF32) {
        const float4* Xv = (const float4*)X;
#pragma unroll
        for (int i = 0; i < 8; ++i) {
            int lin = tid + 256 * i;
            int r = lin >> 5, c4 = lin & 31;
            float4 v = make_float4(0.f, 0.f, 0.f, 0.f);
            if (row0 + r < n) v = Xv[(size_t)(row0 + r) * 32 + c4];
            ushort4 o;
            o.x = f2bf_u(v.x); o.y = f2bf_u(v.y); o.z = f2bf_u(v.z); o.w = f2bf_u(v.w);
            *(ushort4*)&Xs[r][c4 * 4] = o;
        }
    } else {
        const uint4* Xv = (const uint4*)X;
#pragma unroll
        for (int i = 0; i < 4; ++i) {
            int lin = tid + 256 * i;
            int r = lin >> 4, c8 = lin & 15;
            uint4 v = make_uint4(0u, 0u, 0u, 0u);
            if (row0 + r < n) v = Xv[(size_t)(row0 + r) * 16 + c8];
            *(uint4*)&Xs[r][c8 * 8] = v;
        }
    }
    __syncthreads();

    const int lane = tid & 63;
    const int wrow = (tid >> 6) * 16;
    const int m = lane & 15, q = lane >> 4;

    float4v acc[8];
#pragma unroll
    for (int ct = 0; ct < 8; ++ct) acc[ct] = (float4v){0.f, 0.f, 0.f, 0.f};

#pragma unroll
    for (int kt = 0; kt < 4; ++kt) {
        short8v af = *(const short8v*)&Xs[wrow + m][kt * 32 + q * 8];
#pragma unroll
        for (int ct = 0; ct < 8; ++ct) {
            short8v bf = *(const short8v*)&WtS[ct * 16 + m][kt * 32 + q * 8];
            acc[ct] = __builtin_amdgcn_mfma_f32_16x16x32_bf16(af, bf, acc[ct], 0, 0, 0);
        }
    }

    // store H (bf16)
#pragma unroll
    for (int ct = 0; ct < 8; ++ct)
#pragma unroll
        for (int r = 0; r < 4; ++r) {
            int grow = row0 + wrow + q * 4 + r;
            if (grow < n) Hout[(size_t)grow * 128 + ct * 16 + m] = f2bf_u(acc[ct][r]);
        }

    // fused als/ald epilogue (fp32 accumulators)
#pragma unroll
    for (int r = 0; r < 4; ++r) {
        int grow = row0 + wrow + q * 4 + r;
        if (H == 4) {
            float ps[4], pd[4];
#pragma unroll
            for (int hd = 0; hd < 4; ++hd) {
                float x0 = acc[2 * hd][r], x1 = acc[2 * hd + 1][r];
                ps[hd] = x0 * as_s[hd * 32 + m] + x1 * as_s[hd * 32 + 16 + m];
                pd[hd] = x0 * ad_s[hd * 32 + m] + x1 * ad_s[hd * 32 + 16 + m];
#pragma unroll
                for (int o = 1; o < 16; o <<= 1) {
                    ps[hd] += __shfl_xor(ps[hd], o);
                    pd[hd] += __shfl_xor(pd[hd], o);
                }
            }
            if (m == 0 && grow < n) {
#pragma unroll
                for (int hd = 0; hd < 4; ++hd) {
                    als[(size_t)grow * 4 + hd] = ps[hd];
                    ald[(size_t)grow * 4 + hd] = pd[hd];
                }
            }
        } else {
            float ps = 0.f, pd = 0.f;
#pragma unroll
            for (int ct = 0; ct < 8; ++ct) {
                float xv = acc[ct][r];
                ps += xv * as_s[ct * 16 + m];
                pd += xv * ad_s[ct * 16 + m];
            }
#pragma unroll
            for (int o = 1; o < 16; o <<= 1) {
                ps += __shfl_xor(ps, o);
                pd += __shfl_xor(pd, o);
            }
            if (m == 0 && grow < n) { als[grow] = ps; ald[grow] = pd; }
        }
    }
}

// ---------------------------------------------------------------------------
// CSR alloc: block-local scan + one atomicAdd for block base (R14).
// ---------------------------------------------------------------------------
__global__ __launch_bounds__(256) void csr_alloc(const int* __restrict__ cnt,
                                                 int* __restrict__ off,
                                                 int* __restrict__ cursor,
                                                 int* __restrict__ gbase) {
    __shared__ int tmp[256];
    __shared__ int blockBase;
    const int t = threadIdx.x;
    int g = blockIdx.x * 256 + t;
    int v = (g < NN) ? cnt[g] : 0;
    tmp[t] = v;
    __syncthreads();
    for (int ofs = 1; ofs < 256; ofs <<= 1) {
        int add = (t >= ofs) ? tmp[t - ofs] : 0;
        __syncthreads();
        tmp[t] += add;
        __syncthreads();
    }
    if (t == 255) blockBase = atomicAdd(gbase, tmp[255]);
    __syncthreads();
    if (g < NN) {
        int o = blockBase + tmp[t] - v;
        off[g] = o;
        cursor[g] = o;
    }
}

__global__ __launch_bounds__(256) void csr_fill(const int* __restrict__ ei,
                                                int* __restrict__ cursor,
                                                int* __restrict__ csrc) {
    int e = blockIdx.x * 256 + threadIdx.x;
    if (e >= NE) return;
    int s = ei[e], d = ei[NE + e];
    s = min(max(s, 0), NN - 1);
    d = min(max(d, 0), NN - 1);
    int pos = atomicAdd(&cursor[d], 1);
    csrc[pos] = s;
}

// ---------------------------------------------------------------------------
// Aggregate v3 (R17): four 16-lane edge-groups (16B uint4 gathers, shared
// exp -> low instruction count, from v2) x 4-deep batching per group (12
// loads in flight/wave, from R13's lesson that MLP matters). 16 edges per
// round -> deg~13 = 1 round typical. Groups combine via shfl_xor(16,32);
// no LDS, no syncthreads.
// FINAL=0: +bias, ELU, bf16 out. FINAL=1: +bias, fp32 out. No atomics.
// ---------------------------------------------------------------------------
template<int H, int FINAL>
__global__ __launch_bounds__(256) void aggregate(const int* __restrict__ off,
                                                 const int* __restrict__ cnt,
                                                 const int* __restrict__ csrc,
                                                 const unsigned short* __restrict__ h,
                                                 const float* __restrict__ als,
                                                 const float* __restrict__ ald,
                                                 const float* __restrict__ bias,
                                                 void* __restrict__ out) {
    int wid = (int)((blockIdx.x * 256 + threadIdx.x) >> 6);
    int lane = threadIdx.x & 63;
    if (wid >= NN) return;
    const int d = wid;
    const int g = lane >> 4;           // edge group 0..3
    const int c0 = (lane & 15) * 8;    // this lane's 8 channels
    const int hd = (H == 4) ? (c0 >> 5) : 0;
    const float aldd = (H == 4) ? ald[(size_t)d * 4 + hd] : ald[d];

    float acc[8] = {0.f, 0.f, 0.f, 0.f, 0.f, 0.f, 0.f, 0.f};
    float den = 0.f;

    auto expw = [&](float av) {
        float v = av + aldd;
        v = v > 0.f ? v : 0.2f * v;
        return __expf(fminf(v, 60.f));
    };
    auto accum = [&](uint4 hv, float ex) {
        const unsigned short* u = (const unsigned short*)&hv;
#pragma unroll
        for (int i = 0; i < 8; ++i) acc[i] += ex * bf2f_u(u[i]);
        den += ex;
    };

    if (g == 0) {   // self-loop handled by group 0 only
        float av = (H == 4) ? als[(size_t)d * 4 + hd] : als[d];
        uint4 hv = *(const uint4*)&h[(size_t)d * 128 + c0];
        accum(hv, expw(av));
    }

    const int beg = off[d];
    const int end = beg + cnt[d];
    for (int j0 = beg; j0 < end; j0 += 16) {
        int jj[4], idx[4];
#pragma unroll
        for (int k = 0; k < 4; ++k) {
            jj[k] = j0 + 4 * k + g;
            idx[k] = csrc[min(jj[k], end - 1)];
        }
        uint4 hv[4];
#pragma unroll
        for (int k = 0; k < 4; ++k)
            hv[k] = *(const uint4*)&h[(size_t)idx[k] * 128 + c0];
        float av[4];
#pragma unroll
        for (int k = 0; k < 4; ++k)
            av[k] = (H == 4) ? als[(size_t)idx[k] * 4 + hd] : als[idx[k]];
#pragma unroll
        for (int k = 0; k < 4; ++k) {
            float ex = expw(av[k]);
            ex = (jj[k] < end) ? ex : 0.f;       // predicate OOB edges
            accum(hv[k], ex);
        }
    }

    // combine the 4 groups: butterfly over lanes 16, 32 apart
#pragma unroll
    for (int o = 16; o < 64; o <<= 1) {
#pragma unroll
        for (int i = 0; i < 8; ++i) acc[i] += __shfl_xor(acc[i], o);
        den += __shfl_xor(den, o);
    }
    if (g != 0) return;

    const float inv = 1.f / den;
    float4 b0 = *(const float4*)&bias[c0];
    float4 b1 = *(const float4*)&bias[c0 + 4];
    float v[8];
    v[0] = acc[0] * inv + b0.x; v[1] = acc[1] * inv + b0.y;
    v[2] = acc[2] * inv + b0.z; v[3] = acc[3] * inv + b0.w;
    v[4] = acc[4] * inv + b1.x; v[5] = acc[5] * inv + b1.y;
    v[6] = acc[6] * inv + b1.z; v[7] = acc[7] * inv + b1.w;
    if (FINAL) {
        float* op = (float*)out + (size_t)d * 128 + c0;
        *(float4*)op       = make_float4(v[0], v[1], v[2], v[3]);
        *(float4*)(op + 4) = make_float4(v[4], v[5], v[6], v[7]);
    } else {
#pragma unroll
        for (int i = 0; i < 8; ++i) v[i] = v[i] > 0.f ? v[i] : expm1f(v[i]);
        unsigned int p[4];
#pragma unroll
        for (int i = 0; i < 4; ++i)
            p[i] = (unsigned int)f2bf_u(v[2 * i]) | ((unsigned int)f2bf_u(v[2 * i + 1]) << 16);
        *(uint4*)((unsigned short*)out + (size_t)d * 128 + c0) =
            make_uint4(p[0], p[1], p[2], p[3]);
    }
}

// ---------------------------------------------------------------------------
extern "C" void kernel_launch(void* const* d_in, const int* in_sizes, int n_in,
                              void* d_out, int out_size, void* d_ws, size_t ws_size,
                              hipStream_t stream) {
    const float* x      = (const float*)d_in[0];
    const int*   ei     = (const int*)d_in[1];
    const float* W1     = (const float*)d_in[2];
    const float* a_src1 = (const float*)d_in[3];
    const float* a_dst1 = (const float*)d_in[4];
    const float* b1     = (const float*)d_in[5];
    const float* W2     = (const float*)d_in[6];
    const float* a_src2 = (const float*)d_in[7];
    const float* a_dst2 = (const float*)d_in[8];
    const float* b2     = (const float*)d_in[9];

    const int N = NN;

    // Workspace: explicit BYTE offsets, every buffer 16B-aligned.
    char* base = (char*)d_ws;
    int*   cnt    = (int*)(base + 0);          //  50000 i
    int*   gbase  = (int*)(base + 200000);     //      1 i
    int*   off    = (int*)(base + 200016);     //  50000 i
    int*   cursor = (int*)(base + 400016);     //  50000 i
    int*   csrc   = (int*)(base + 602064);     // 600000 i
    float* als    = (float*)(base + 3002064);  // 200000 f
    float* ald    = (float*)(base + 3802064);  // 200000 f
    unsigned short* h   = (unsigned short*)(base + 4602064);   // N*128 bf16
    unsigned short* x2  = (unsigned short*)(base + 17402064);  // N*128 bf16
    unsigned short* wt1 = (unsigned short*)(base + 30202064);  // 16384 bf16
    unsigned short* wt2 = (unsigned short*)(base + 30234832);  // 16384 bf16
    // total ~30.27 MB

    const int gemmGrid  = (N + 63) / 64;          // 782
    const int edgeGrid  = (NE + 255) / 256;       // 2344
    const int allocGrid = (N + 255) / 256;        // 196
    const int aggGrid   = (N * 64 + 255) / 256;   // 12500

    prep_zero<<<128 + allocGrid, 256, 0, stream>>>(W1, W2, wt1, wt2, cnt, gbase);
    csr_count<<<edgeGrid, 256, 0, stream>>>(ei, cnt);
    gemm_fused<4, 1><<<gemmGrid, 256, 0, stream>>>(x, wt1, a_src1, a_dst1, h, als, ald, N);
    csr_alloc<<<allocGrid, 256, 0, stream>>>(cnt, off, cursor, gbase);
    csr_fill<<<edgeGrid, 256, 0, stream>>>(ei, cursor, csrc);

    aggregate<4, 0><<<aggGrid, 256, 0, stream>>>(off, cnt, csrc, h, als, ald, b1, x2);
    gemm_fused<1, 0><<<gemmGrid, 256, 0, stream>>>(x2, wt2, a_src2, a_dst2, h, als, ald, N);
    aggregate<1, 1><<<aggGrid, 256, 0, stream>>>(off, cnt, csrc, h, als, ald, b2, d_out);
}